// Round 1
// baseline (166.447 us; speedup 1.0000x reference)
//
#include <hip/hip_runtime.h>

constexpr int D  = 128;   // feature dim (= H*F)
constexpr int NH = 4;     // heads
constexpr int NF = 32;    // features per head

// pack two fp32 -> two bf16 (RNE) in one u32 (lo = a, hi = b)
__device__ __forceinline__ unsigned pack_bf2(float a, float b) {
    unsigned ua = __float_as_uint(a), ub = __float_as_uint(b);
    ua += 0x7fffu + ((ua >> 16) & 1u);
    ub += 0x7fffu + ((ub >> 16) & 1u);
    return (ua >> 16) | (ub & 0xffff0000u);
}

// ---- zero the histogram counters (replaces 43us rocclr fillBufferAligned) ----
__global__ __launch_bounds__(256) void zero_cnt_kernel(int* __restrict__ p, int n)
{
    const int i4 = (blockIdx.x * blockDim.x + threadIdx.x) * 4;
    if (i4 + 3 < n) {
        *(int4*)&p[i4] = {0, 0, 0, 0};
    } else if (i4 < n) {
        for (int i = i4; i < n; ++i) p[i] = 0;
    }
}

// ---- Dense(128->128) + LayerNorm + ReLU ----
// fp32 GEMM, BM=64 x BN=128, BK=32, 128 threads, 8x8 register tile per thread.
template<bool BF16OUT>
__global__ __launch_bounds__(128) void dense_ln_relu_kernel(
    const float* __restrict__ X, const float* __restrict__ W,
    const float* __restrict__ bias, const float* __restrict__ gam,
    const float* __restrict__ bet, void* __restrict__ Yv, int N)
{
    constexpr int BM = 64, BK = 32, XS = 68;
    __shared__ float Xl[BK * XS];              // [k][row]
    __shared__ float Wl[BK * 128];             // [k][c]

    const int tid = threadIdx.x;
    const int tx = tid & 15;
    const int ty = tid >> 4;
    const int n0 = blockIdx.x * BM;
    const int r0 = ty * 8;
    const int c0 = tx * 4;

    float4 acc0[8], acc1[8];
    #pragma unroll
    for (int i = 0; i < 8; ++i) { acc0[i] = {0,0,0,0}; acc1[i] = {0,0,0,0}; }

    for (int kc = 0; kc < D; kc += BK) {
        #pragma unroll
        for (int j = 0; j < 4; ++j) {
            const int i = tid + 128 * j;
            const int row = i >> 3;
            const int kk = (i & 7) * 4;
            float4 v = {0,0,0,0};
            if (n0 + row < N)
                v = *(const float4*)&X[(size_t)(n0 + row) * D + kc + kk];
            Xl[(kk + 0) * XS + row] = v.x;
            Xl[(kk + 1) * XS + row] = v.y;
            Xl[(kk + 2) * XS + row] = v.z;
            Xl[(kk + 3) * XS + row] = v.w;
        }
        #pragma unroll
        for (int j = 0; j < 8; ++j) {
            const int i = tid + 128 * j;
            *(float4*)&Wl[i * 4] = *(const float4*)&W[(size_t)kc * D + i * 4];
        }
        __syncthreads();

        #pragma unroll 4
        for (int k = 0; k < BK; ++k) {
            const float4 xv0 = *(const float4*)&Xl[k * XS + r0];
            const float4 xv1 = *(const float4*)&Xl[k * XS + r0 + 4];
            const float4 wv0 = *(const float4*)&Wl[k * 128 + c0];
            const float4 wv1 = *(const float4*)&Wl[k * 128 + c0 + 64];
            const float xr[8] = {xv0.x, xv0.y, xv0.z, xv0.w,
                                 xv1.x, xv1.y, xv1.z, xv1.w};
            #pragma unroll
            for (int i = 0; i < 8; ++i) {
                acc0[i].x = fmaf(xr[i], wv0.x, acc0[i].x);
                acc0[i].y = fmaf(xr[i], wv0.y, acc0[i].y);
                acc0[i].z = fmaf(xr[i], wv0.z, acc0[i].z);
                acc0[i].w = fmaf(xr[i], wv0.w, acc0[i].w);
                acc1[i].x = fmaf(xr[i], wv1.x, acc1[i].x);
                acc1[i].y = fmaf(xr[i], wv1.y, acc1[i].y);
                acc1[i].z = fmaf(xr[i], wv1.z, acc1[i].z);
                acc1[i].w = fmaf(xr[i], wv1.w, acc1[i].w);
            }
        }
        __syncthreads();
    }

    const float4 bv0 = *(const float4*)&bias[c0];
    const float4 bv1 = *(const float4*)&bias[c0 + 64];
    const float4 gv0 = *(const float4*)&gam[c0];
    const float4 gv1 = *(const float4*)&gam[c0 + 64];
    const float4 tv0 = *(const float4*)&bet[c0];
    const float4 tv1 = *(const float4*)&bet[c0 + 64];

    #pragma unroll
    for (int i = 0; i < 8; ++i) {
        float4 a = acc0[i], b = acc1[i];
        a.x += bv0.x; a.y += bv0.y; a.z += bv0.z; a.w += bv0.w;
        b.x += bv1.x; b.y += bv1.y; b.z += bv1.z; b.w += bv1.w;
        float s  = a.x + a.y + a.z + a.w + b.x + b.y + b.z + b.w;
        float ss = a.x*a.x + a.y*a.y + a.z*a.z + a.w*a.w
                 + b.x*b.x + b.y*b.y + b.z*b.z + b.w*b.w;
        #pragma unroll
        for (int off = 1; off <= 8; off <<= 1) {
            s  += __shfl_xor(s,  off, 16);
            ss += __shfl_xor(ss, off, 16);
        }
        const float mu   = s * (1.f / 128.f);
        const float var  = fmaxf(ss * (1.f / 128.f) - mu * mu, 0.f);
        const float rstd = rsqrtf(var + 1e-6f);
        const int row = n0 + r0 + i;
        if (row < N) {
            float4 o0, o1;
            o0.x = fmaxf((a.x - mu) * rstd * gv0.x + tv0.x, 0.f);
            o0.y = fmaxf((a.y - mu) * rstd * gv0.y + tv0.y, 0.f);
            o0.z = fmaxf((a.z - mu) * rstd * gv0.z + tv0.z, 0.f);
            o0.w = fmaxf((a.w - mu) * rstd * gv0.w + tv0.w, 0.f);
            o1.x = fmaxf((b.x - mu) * rstd * gv1.x + tv1.x, 0.f);
            o1.y = fmaxf((b.y - mu) * rstd * gv1.y + tv1.y, 0.f);
            o1.z = fmaxf((b.z - mu) * rstd * gv1.z + tv1.z, 0.f);
            o1.w = fmaxf((b.w - mu) * rstd * gv1.w + tv1.w, 0.f);
            if constexpr (BF16OUT) {
                unsigned short* Y = (unsigned short*)Yv;
                uint2 p0, p1;
                p0.x = pack_bf2(o0.x, o0.y); p0.y = pack_bf2(o0.z, o0.w);
                p1.x = pack_bf2(o1.x, o1.y); p1.y = pack_bf2(o1.z, o1.w);
                *(uint2*)&Y[(size_t)row * D + c0]      = p0;
                *(uint2*)&Y[(size_t)row * D + c0 + 64] = p1;
            } else {
                float* Y = (float*)Yv;
                *(float4*)&Y[(size_t)row * D + c0]      = o0;
                *(float4*)&Y[(size_t)row * D + c0 + 64] = o1;
            }
        }
    }
}

// ---- CSR build: histogram ----
__global__ __launch_bounds__(256) void hist_kernel(
    const int* __restrict__ recv, int* __restrict__ cnt, int E)
{
    int i = blockIdx.x * blockDim.x + threadIdx.x;
    if (i < E) atomicAdd(&cnt[recv[i]], 1);
}

// ---- CSR build: per-1024-chunk exclusive scan ----
__global__ __launch_bounds__(256) void scan_blocks_kernel(
    const int* __restrict__ cnt, int* __restrict__ rowptr,
    int* __restrict__ bsum, int N)
{
    __shared__ int lds[256];
    const int tid = threadIdx.x;
    const int base = blockIdx.x * 1024 + tid * 4;
    int v0 = (base + 0 < N) ? cnt[base + 0] : 0;
    int v1 = (base + 1 < N) ? cnt[base + 1] : 0;
    int v2 = (base + 2 < N) ? cnt[base + 2] : 0;
    int v3 = (base + 3 < N) ? cnt[base + 3] : 0;
    const int tsum = v0 + v1 + v2 + v3;
    lds[tid] = tsum;
    __syncthreads();
    for (int off = 1; off < 256; off <<= 1) {
        int t = (tid >= off) ? lds[tid - off] : 0;
        __syncthreads();
        lds[tid] += t;
        __syncthreads();
    }
    int run = lds[tid] - tsum;
    if (base + 0 < N) rowptr[base + 0] = run;
    run += v0;
    if (base + 1 < N) rowptr[base + 1] = run;
    run += v1;
    if (base + 2 < N) rowptr[base + 2] = run;
    run += v2;
    if (base + 3 < N) rowptr[base + 3] = run;
    if (tid == 255) bsum[blockIdx.x] = lds[255];
}

// ---- CSR build: scan block sums ----
__global__ __launch_bounds__(256) void scan_top_kernel(int* bsum, int nb)
{
    __shared__ int lds[256];
    const int tid = threadIdx.x;
    int v = (tid < nb) ? bsum[tid] : 0;
    lds[tid] = v;
    __syncthreads();
    for (int off = 1; off < 256; off <<= 1) {
        int t = (tid >= off) ? lds[tid - off] : 0;
        __syncthreads();
        lds[tid] += t;
        __syncthreads();
    }
    if (tid < nb) bsum[tid] = lds[tid] - v;
}

// ---- CSR build: add chunk offsets ----
__global__ __launch_bounds__(256) void scan_add_kernel(
    int* __restrict__ rowptr, int* __restrict__ cursor,
    const int* __restrict__ bsum, int N, int E)
{
    int i = blockIdx.x * blockDim.x + threadIdx.x;
    if (i < N) {
        int v = rowptr[i] + bsum[i >> 10];
        rowptr[i] = v;
        cursor[i] = v;
    }
    if (i == 0) rowptr[N] = E;
}

// ---- CSR build: bucket-fill sorted sender ids ----
__global__ __launch_bounds__(256) void fill_kernel(
    const int* __restrict__ senders, const int* __restrict__ receivers,
    int* __restrict__ cursor, int* __restrict__ ssend, int E)
{
    int e = blockIdx.x * blockDim.x + threadIdx.x;
    if (e < E) {
        int r = receivers[e];
        int pos = atomicAdd(&cursor[r], 1);
        ssend[pos] = senders[e];
    }
}

// ---- fused per-node attention (bf16 q) ----
// wave64 per node; each 32-lane half processes even/odd edges with its own
// online-softmax state (independent per 8-lane head group), merged at end.
// lane-in-half hl holds dims 4*hl .. 4*hl+3 (bf16), head = hl>>3.
__global__ __launch_bounds__(256) void node_attn_kernel(
    const unsigned short* __restrict__ q, const int* __restrict__ rowptr,
    const int* __restrict__ ssend, float* __restrict__ out, int N)
{
    const int lane = threadIdx.x & 63;
    const int hl   = lane & 31;
    const int half = lane >> 5;
    const int wid  = (blockIdx.x * blockDim.x + threadIdx.x) >> 6;
    const int nw   = (gridDim.x * blockDim.x) >> 6;

    for (int n = wid; n < N; n += nw) {
        const uint2 braw = *(const uint2*)&q[(size_t)n * D + hl * 4];
        const float b0 = __uint_as_float(braw.x << 16);
        const float b1 = __uint_as_float(braw.x & 0xffff0000u);
        const float b2 = __uint_as_float(braw.y << 16);
        const float b3 = __uint_as_float(braw.y & 0xffff0000u);

        const int beg = rowptr[n], end = rowptr[n + 1];
        float m = -1e30f, l = 0.f;
        float c0 = 0.f, c1 = 0.f, c2 = 0.f, c3 = 0.f;

        int j = beg + half;
        uint2 raw = {0u, 0u};
        if (j < end)
            raw = *(const uint2*)&q[(size_t)ssend[j] * D + hl * 4];
        for (; j < end; j += 2) {
            const uint2 cur = raw;
            if (j + 2 < end)
                raw = *(const uint2*)&q[(size_t)ssend[j + 2] * D + hl * 4];
            const float a0 = __uint_as_float(cur.x << 16);
            const float a1 = __uint_as_float(cur.x & 0xffff0000u);
            const float a2 = __uint_as_float(cur.y << 16);
            const float a3 = __uint_as_float(cur.y & 0xffff0000u);
            float p = a0 * b0 + a1 * b1 + a2 * b2 + a3 * b3;
            p += __shfl_xor(p, 1);
            p += __shfl_xor(p, 2);
            p += __shfl_xor(p, 4);
            const float logit = p * 0.17677669529663687f;   // 1/sqrt(32)
            const float nm = fmaxf(m, logit);
            const float sc = __expf(m - nm);
            const float u  = __expf(logit - nm);
            l  = l * sc + u;
            c0 = c0 * sc + u * a0;
            c1 = c1 * sc + u * a1;
            c2 = c2 * sc + u * a2;
            c3 = c3 * sc + u * a3;
            m = nm;
        }

        // merge the two halves' states (flash-attention merge)
        const float om  = __shfl_xor(m, 32);
        const float ol  = __shfl_xor(l, 32);
        const float oc0 = __shfl_xor(c0, 32);
        const float oc1 = __shfl_xor(c1, 32);
        const float oc2 = __shfl_xor(c2, 32);
        const float oc3 = __shfl_xor(c3, 32);
        const float nm = fmaxf(m, om);
        const float s0 = __expf(m - nm), s1 = __expf(om - nm);
        const float lt = l * s0 + ol * s1;
        const float inv = (lt > 0.f) ? (1.f / lt) : 0.f;
        float r0 = fmaxf((c0 * s0 + oc0 * s1) * inv, 0.f);
        float r1 = fmaxf((c1 * s0 + oc1 * s1) * inv, 0.f);
        float r2 = fmaxf((c2 * s0 + oc2 * s1) * inv, 0.f);
        float r3 = fmaxf((c3 * s0 + oc3 * s1) * inv, 0.f);

        // head-mean: lanes hl, hl^8, hl^16, hl^24 hold heads 0..3 of same f
        r0 += __shfl_xor(r0, 8);  r0 += __shfl_xor(r0, 16);
        r1 += __shfl_xor(r1, 8);  r1 += __shfl_xor(r1, 16);
        r2 += __shfl_xor(r2, 8);  r2 += __shfl_xor(r2, 16);
        r3 += __shfl_xor(r3, 8);  r3 += __shfl_xor(r3, 16);
        if (lane < 8) {
            float4 o = {0.25f * r0, 0.25f * r1, 0.25f * r2, 0.25f * r3};
            *(float4*)&out[(size_t)n * NF + lane * 4] = o;
        }
    }
}

extern "C" void kernel_launch(void* const* d_in, const int* in_sizes, int n_in,
                              void* d_out, int out_size, void* d_ws, size_t ws_size,
                              hipStream_t stream)
{
    const float* nodes = (const float*)d_in[0];
    const float* W1    = (const float*)d_in[1];
    const float* b1    = (const float*)d_in[2];
    const float* g1    = (const float*)d_in[3];
    const float* be1   = (const float*)d_in[4];
    const float* W2    = (const float*)d_in[5];
    const float* b2    = (const float*)d_in[6];
    const float* g2    = (const float*)d_in[7];
    const float* be2   = (const float*)d_in[8];
    const int* senders   = (const int*)d_in[9];
    const int* receivers = (const int*)d_in[10];

    const int N = in_sizes[0] / D;
    const int E = in_sizes[9];
    float* out = (float*)d_out;

    char* ws = (char*)d_ws;
    float* A            = (float*)ws;  ws += (size_t)N * D * 4;
    unsigned short* qb  = (unsigned short*)ws; ws += (size_t)N * D * 2;
    int* cnt      = (int*)ws;    ws += (size_t)N * 4;
    int* rowptr   = (int*)ws;    ws += (size_t)(N + 2) * 4;
    int* cursor   = (int*)ws;    ws += (size_t)N * 4;
    int* bsum     = (int*)ws;    ws += 256 * 4;
    int* ssend    = (int*)ws;    ws += (size_t)E * 4;

    // custom zero (rocclr fillBufferAligned measured 43us for this 200KB fill)
    zero_cnt_kernel<<<(N / 4 + 255) / 256, 256, 0, stream>>>(cnt, N);

    // MLP: layer1 fp32 -> layer2 writes bf16 q
    const int gblk = (N + 63) / 64;
    dense_ln_relu_kernel<false><<<gblk, 128, 0, stream>>>(nodes, W1, b1, g1, be1, A, N);
    dense_ln_relu_kernel<true ><<<gblk, 128, 0, stream>>>(A, W2, b2, g2, be2, qb, N);

    // CSR build (receiver-sorted sender list)
    const int nb = (N + 1023) / 1024;
    hist_kernel<<<(E + 255) / 256, 256, 0, stream>>>(receivers, cnt, E);
    scan_blocks_kernel<<<nb, 256, 0, stream>>>(cnt, rowptr, bsum, N);
    scan_top_kernel<<<1, 256, 0, stream>>>(bsum, nb);
    scan_add_kernel<<<(N + 255) / 256, 256, 0, stream>>>(rowptr, cursor, bsum, N, E);
    fill_kernel<<<(E + 255) / 256, 256, 0, stream>>>(senders, receivers, cursor, ssend, E);

    // fused attention + epilogue
    node_attn_kernel<<<(N + 3) / 4, 256, 0, stream>>>(qb, rowptr, ssend, out, N);
}

// Round 2
// 164.578 us; speedup vs baseline: 1.0114x; 1.0114x over previous
//
#include <hip/hip_runtime.h>

constexpr int D  = 128;   // feature dim (= H*F)
constexpr int NH = 4;     // heads
constexpr int NF = 32;    // features per head

// pack two fp32 -> two bf16 (RNE) in one u32 (lo = a, hi = b)
__device__ __forceinline__ unsigned pack_bf2(float a, float b) {
    unsigned ua = __float_as_uint(a), ub = __float_as_uint(b);
    ua += 0x7fffu + ((ua >> 16) & 1u);
    ub += 0x7fffu + ((ub >> 16) & 1u);
    return (ua >> 16) | (ub & 0xffff0000u);
}

// ---- zero the histogram counters ----
__global__ __launch_bounds__(256) void zero_cnt_kernel(int* __restrict__ p, int n)
{
    const int i4 = (blockIdx.x * blockDim.x + threadIdx.x) * 4;
    if (i4 + 3 < n) {
        *(int4*)&p[i4] = {0, 0, 0, 0};
    } else if (i4 < n) {
        for (int i = i4; i < n; ++i) p[i] = 0;
    }
}

// ---- Fused MLP: [Dense(128->128) + LN + ReLU] x 2, bf16 output ----
// 256 threads, BM=64 rows/block. Per-thread 4 rows x 8 cols register tile.
// h1 kept on-chip in LDS (transposed [k][row]) -> no fp32 intermediate in HBM.
// LDS: Wl 16KB + U 34.8KB = 50KB -> 3 blocks/CU; launch_bounds(256,6) caps
// VGPR at 85 so 24 waves/CU (37.5% occ) vs 11% for the old 2-kernel version.
__global__ __launch_bounds__(256, 6) void fused_mlp_kernel(
    const float* __restrict__ X,
    const float* __restrict__ W1, const float* __restrict__ b1,
    const float* __restrict__ g1, const float* __restrict__ be1,
    const float* __restrict__ W2, const float* __restrict__ b2,
    const float* __restrict__ g2, const float* __restrict__ be2,
    unsigned short* __restrict__ Q, int N)
{
    constexpr int BM = 64, BK = 32, XS = 68;
    __shared__ float Wl[BK * 128];   // weight tile [k][c], reused W1 then W2
    __shared__ float U[128 * XS];    // union: X tile [k<32][row] / h1 [k<128][row]

    const int tid = threadIdx.x;
    const int tx = tid & 15;
    const int ty = tid >> 4;
    const int n0 = blockIdx.x * BM;
    const int r0 = ty * 4;           // 4 rows per thread
    const int c0 = tx * 4;           // cols c0..c0+3 and c0+64..c0+67

    float4 accA[4], accB[4];
    #pragma unroll
    for (int i = 0; i < 4; ++i) { accA[i] = {0,0,0,0}; accB[i] = {0,0,0,0}; }

    // ================= GEMM1: X @ W1 =================
    for (int kc = 0; kc < D; kc += BK) {
        #pragma unroll
        for (int j = 0; j < 2; ++j) {
            const int idx = tid + 256 * j;       // 512 float4 loads
            const int row = idx >> 3;            // 0..63
            const int kk = (idx & 7) * 4;        // 0..28
            float4 v = {0,0,0,0};
            if (n0 + row < N)
                v = *(const float4*)&X[(size_t)(n0 + row) * D + kc + kk];
            U[(kk + 0) * XS + row] = v.x;
            U[(kk + 1) * XS + row] = v.y;
            U[(kk + 2) * XS + row] = v.z;
            U[(kk + 3) * XS + row] = v.w;
        }
        #pragma unroll
        for (int j = 0; j < 4; ++j) {
            const int i = tid + 256 * j;         // 1024 float4 loads
            *(float4*)&Wl[i * 4] = *(const float4*)&W1[(size_t)kc * D + i * 4];
        }
        __syncthreads();

        #pragma unroll 4
        for (int k = 0; k < BK; ++k) {
            const float4 xv  = *(const float4*)&U[k * XS + r0];
            const float4 wv0 = *(const float4*)&Wl[k * 128 + c0];
            const float4 wv1 = *(const float4*)&Wl[k * 128 + c0 + 64];
            const float xr[4] = {xv.x, xv.y, xv.z, xv.w};
            #pragma unroll
            for (int i = 0; i < 4; ++i) {
                accA[i].x = fmaf(xr[i], wv0.x, accA[i].x);
                accA[i].y = fmaf(xr[i], wv0.y, accA[i].y);
                accA[i].z = fmaf(xr[i], wv0.z, accA[i].z);
                accA[i].w = fmaf(xr[i], wv0.w, accA[i].w);
                accB[i].x = fmaf(xr[i], wv1.x, accB[i].x);
                accB[i].y = fmaf(xr[i], wv1.y, accB[i].y);
                accB[i].z = fmaf(xr[i], wv1.z, accB[i].z);
                accB[i].w = fmaf(xr[i], wv1.w, accB[i].w);
            }
        }
        __syncthreads();
    }

    // ================= LN1 + ReLU -> h1 into U ([k][row]) =================
    {
        const float4 bv0 = *(const float4*)&b1[c0];
        const float4 bv1 = *(const float4*)&b1[c0 + 64];
        const float4 gv0 = *(const float4*)&g1[c0];
        const float4 gv1 = *(const float4*)&g1[c0 + 64];
        const float4 tv0 = *(const float4*)&be1[c0];
        const float4 tv1 = *(const float4*)&be1[c0 + 64];
        #pragma unroll
        for (int i = 0; i < 4; ++i) {
            float4 a = accA[i], b = accB[i];
            a.x += bv0.x; a.y += bv0.y; a.z += bv0.z; a.w += bv0.w;
            b.x += bv1.x; b.y += bv1.y; b.z += bv1.z; b.w += bv1.w;
            float s  = a.x + a.y + a.z + a.w + b.x + b.y + b.z + b.w;
            float ss = a.x*a.x + a.y*a.y + a.z*a.z + a.w*a.w
                     + b.x*b.x + b.y*b.y + b.z*b.z + b.w*b.w;
            #pragma unroll
            for (int off = 1; off <= 8; off <<= 1) {
                s  += __shfl_xor(s,  off, 16);
                ss += __shfl_xor(ss, off, 16);
            }
            const float mu   = s * (1.f / 128.f);
            const float var  = fmaxf(ss * (1.f / 128.f) - mu * mu, 0.f);
            const float rstd = rsqrtf(var + 1e-6f);
            const int row = r0 + i;
            U[(c0 + 0)  * XS + row] = fmaxf((a.x - mu) * rstd * gv0.x + tv0.x, 0.f);
            U[(c0 + 1)  * XS + row] = fmaxf((a.y - mu) * rstd * gv0.y + tv0.y, 0.f);
            U[(c0 + 2)  * XS + row] = fmaxf((a.z - mu) * rstd * gv0.z + tv0.z, 0.f);
            U[(c0 + 3)  * XS + row] = fmaxf((a.w - mu) * rstd * gv0.w + tv0.w, 0.f);
            U[(c0 + 64) * XS + row] = fmaxf((b.x - mu) * rstd * gv1.x + tv1.x, 0.f);
            U[(c0 + 65) * XS + row] = fmaxf((b.y - mu) * rstd * gv1.y + tv1.y, 0.f);
            U[(c0 + 66) * XS + row] = fmaxf((b.z - mu) * rstd * gv1.z + tv1.z, 0.f);
            U[(c0 + 67) * XS + row] = fmaxf((b.w - mu) * rstd * gv1.w + tv1.w, 0.f);
        }
    }

    // ================= GEMM2: h1 @ W2 =================
    #pragma unroll
    for (int i = 0; i < 4; ++i) { accA[i] = {0,0,0,0}; accB[i] = {0,0,0,0}; }

    for (int kc = 0; kc < D; kc += BK) {
        #pragma unroll
        for (int j = 0; j < 4; ++j) {
            const int i = tid + 256 * j;
            *(float4*)&Wl[i * 4] = *(const float4*)&W2[(size_t)kc * D + i * 4];
        }
        __syncthreads();   // orders h1 writes (kc==0) + Wl writes before reads

        #pragma unroll 4
        for (int k = 0; k < BK; ++k) {
            const float4 xv  = *(const float4*)&U[(kc + k) * XS + r0];
            const float4 wv0 = *(const float4*)&Wl[k * 128 + c0];
            const float4 wv1 = *(const float4*)&Wl[k * 128 + c0 + 64];
            const float xr[4] = {xv.x, xv.y, xv.z, xv.w};
            #pragma unroll
            for (int i = 0; i < 4; ++i) {
                accA[i].x = fmaf(xr[i], wv0.x, accA[i].x);
                accA[i].y = fmaf(xr[i], wv0.y, accA[i].y);
                accA[i].z = fmaf(xr[i], wv0.z, accA[i].z);
                accA[i].w = fmaf(xr[i], wv0.w, accA[i].w);
                accB[i].x = fmaf(xr[i], wv1.x, accB[i].x);
                accB[i].y = fmaf(xr[i], wv1.y, accB[i].y);
                accB[i].z = fmaf(xr[i], wv1.z, accB[i].z);
                accB[i].w = fmaf(xr[i], wv1.w, accB[i].w);
            }
        }
        __syncthreads();
    }

    // ================= LN2 + ReLU -> bf16 q =================
    {
        const float4 bv0 = *(const float4*)&b2[c0];
        const float4 bv1 = *(const float4*)&b2[c0 + 64];
        const float4 gv0 = *(const float4*)&g2[c0];
        const float4 gv1 = *(const float4*)&g2[c0 + 64];
        const float4 tv0 = *(const float4*)&be2[c0];
        const float4 tv1 = *(const float4*)&be2[c0 + 64];
        #pragma unroll
        for (int i = 0; i < 4; ++i) {
            float4 a = accA[i], b = accB[i];
            a.x += bv0.x; a.y += bv0.y; a.z += bv0.z; a.w += bv0.w;
            b.x += bv1.x; b.y += bv1.y; b.z += bv1.z; b.w += bv1.w;
            float s  = a.x + a.y + a.z + a.w + b.x + b.y + b.z + b.w;
            float ss = a.x*a.x + a.y*a.y + a.z*a.z + a.w*a.w
                     + b.x*b.x + b.y*b.y + b.z*b.z + b.w*b.w;
            #pragma unroll
            for (int off = 1; off <= 8; off <<= 1) {
                s  += __shfl_xor(s,  off, 16);
                ss += __shfl_xor(ss, off, 16);
            }
            const float mu   = s * (1.f / 128.f);
            const float var  = fmaxf(ss * (1.f / 128.f) - mu * mu, 0.f);
            const float rstd = rsqrtf(var + 1e-6f);
            const int row = n0 + r0 + i;
            if (row < N) {
                float o0x = fmaxf((a.x - mu) * rstd * gv0.x + tv0.x, 0.f);
                float o0y = fmaxf((a.y - mu) * rstd * gv0.y + tv0.y, 0.f);
                float o0z = fmaxf((a.z - mu) * rstd * gv0.z + tv0.z, 0.f);
                float o0w = fmaxf((a.w - mu) * rstd * gv0.w + tv0.w, 0.f);
                float o1x = fmaxf((b.x - mu) * rstd * gv1.x + tv1.x, 0.f);
                float o1y = fmaxf((b.y - mu) * rstd * gv1.y + tv1.y, 0.f);
                float o1z = fmaxf((b.z - mu) * rstd * gv1.z + tv1.z, 0.f);
                float o1w = fmaxf((b.w - mu) * rstd * gv1.w + tv1.w, 0.f);
                uint2 p0, p1;
                p0.x = pack_bf2(o0x, o0y); p0.y = pack_bf2(o0z, o0w);
                p1.x = pack_bf2(o1x, o1y); p1.y = pack_bf2(o1z, o1w);
                *(uint2*)&Q[(size_t)row * D + c0]      = p0;
                *(uint2*)&Q[(size_t)row * D + c0 + 64] = p1;
            }
        }
    }
}

// ---- CSR build: histogram ----
__global__ __launch_bounds__(256) void hist_kernel(
    const int* __restrict__ recv, int* __restrict__ cnt, int E)
{
    int i = blockIdx.x * blockDim.x + threadIdx.x;
    if (i < E) atomicAdd(&cnt[recv[i]], 1);
}

// ---- CSR build: per-1024-chunk exclusive scan ----
__global__ __launch_bounds__(256) void scan_blocks_kernel(
    const int* __restrict__ cnt, int* __restrict__ rowptr,
    int* __restrict__ bsum, int N)
{
    __shared__ int lds[256];
    const int tid = threadIdx.x;
    const int base = blockIdx.x * 1024 + tid * 4;
    int v0 = (base + 0 < N) ? cnt[base + 0] : 0;
    int v1 = (base + 1 < N) ? cnt[base + 1] : 0;
    int v2 = (base + 2 < N) ? cnt[base + 2] : 0;
    int v3 = (base + 3 < N) ? cnt[base + 3] : 0;
    const int tsum = v0 + v1 + v2 + v3;
    lds[tid] = tsum;
    __syncthreads();
    for (int off = 1; off < 256; off <<= 1) {
        int t = (tid >= off) ? lds[tid - off] : 0;
        __syncthreads();
        lds[tid] += t;
        __syncthreads();
    }
    int run = lds[tid] - tsum;
    if (base + 0 < N) rowptr[base + 0] = run;
    run += v0;
    if (base + 1 < N) rowptr[base + 1] = run;
    run += v1;
    if (base + 2 < N) rowptr[base + 2] = run;
    run += v2;
    if (base + 3 < N) rowptr[base + 3] = run;
    if (tid == 255) bsum[blockIdx.x] = lds[255];
}

// ---- CSR build: scan block sums ----
__global__ __launch_bounds__(256) void scan_top_kernel(int* bsum, int nb)
{
    __shared__ int lds[256];
    const int tid = threadIdx.x;
    int v = (tid < nb) ? bsum[tid] : 0;
    lds[tid] = v;
    __syncthreads();
    for (int off = 1; off < 256; off <<= 1) {
        int t = (tid >= off) ? lds[tid - off] : 0;
        __syncthreads();
        lds[tid] += t;
        __syncthreads();
    }
    if (tid < nb) bsum[tid] = lds[tid] - v;
}

// ---- CSR build: add chunk offsets ----
__global__ __launch_bounds__(256) void scan_add_kernel(
    int* __restrict__ rowptr, int* __restrict__ cursor,
    const int* __restrict__ bsum, int N, int E)
{
    int i = blockIdx.x * blockDim.x + threadIdx.x;
    if (i < N) {
        int v = rowptr[i] + bsum[i >> 10];
        rowptr[i] = v;
        cursor[i] = v;
    }
    if (i == 0) rowptr[N] = E;
}

// ---- CSR build: bucket-fill sorted sender ids ----
__global__ __launch_bounds__(256) void fill_kernel(
    const int* __restrict__ senders, const int* __restrict__ receivers,
    int* __restrict__ cursor, int* __restrict__ ssend, int E)
{
    int e = blockIdx.x * blockDim.x + threadIdx.x;
    if (e < E) {
        int r = receivers[e];
        int pos = atomicAdd(&cursor[r], 1);
        ssend[pos] = senders[e];
    }
}

// ---- fused per-node attention (bf16 q) ----
__global__ __launch_bounds__(256) void node_attn_kernel(
    const unsigned short* __restrict__ q, const int* __restrict__ rowptr,
    const int* __restrict__ ssend, float* __restrict__ out, int N)
{
    const int lane = threadIdx.x & 63;
    const int hl   = lane & 31;
    const int half = lane >> 5;
    const int wid  = (blockIdx.x * blockDim.x + threadIdx.x) >> 6;
    const int nw   = (gridDim.x * blockDim.x) >> 6;

    for (int n = wid; n < N; n += nw) {
        const uint2 braw = *(const uint2*)&q[(size_t)n * D + hl * 4];
        const float b0 = __uint_as_float(braw.x << 16);
        const float b1 = __uint_as_float(braw.x & 0xffff0000u);
        const float b2 = __uint_as_float(braw.y << 16);
        const float b3 = __uint_as_float(braw.y & 0xffff0000u);

        const int beg = rowptr[n], end = rowptr[n + 1];
        float m = -1e30f, l = 0.f;
        float c0 = 0.f, c1 = 0.f, c2 = 0.f, c3 = 0.f;

        int j = beg + half;
        uint2 raw = {0u, 0u};
        if (j < end)
            raw = *(const uint2*)&q[(size_t)ssend[j] * D + hl * 4];
        for (; j < end; j += 2) {
            const uint2 cur = raw;
            if (j + 2 < end)
                raw = *(const uint2*)&q[(size_t)ssend[j + 2] * D + hl * 4];
            const float a0 = __uint_as_float(cur.x << 16);
            const float a1 = __uint_as_float(cur.x & 0xffff0000u);
            const float a2 = __uint_as_float(cur.y << 16);
            const float a3 = __uint_as_float(cur.y & 0xffff0000u);
            float p = a0 * b0 + a1 * b1 + a2 * b2 + a3 * b3;
            p += __shfl_xor(p, 1);
            p += __shfl_xor(p, 2);
            p += __shfl_xor(p, 4);
            const float logit = p * 0.17677669529663687f;   // 1/sqrt(32)
            const float nm = fmaxf(m, logit);
            const float sc = __expf(m - nm);
            const float u  = __expf(logit - nm);
            l  = l * sc + u;
            c0 = c0 * sc + u * a0;
            c1 = c1 * sc + u * a1;
            c2 = c2 * sc + u * a2;
            c3 = c3 * sc + u * a3;
            m = nm;
        }

        const float om  = __shfl_xor(m, 32);
        const float ol  = __shfl_xor(l, 32);
        const float oc0 = __shfl_xor(c0, 32);
        const float oc1 = __shfl_xor(c1, 32);
        const float oc2 = __shfl_xor(c2, 32);
        const float oc3 = __shfl_xor(c3, 32);
        const float nm = fmaxf(m, om);
        const float s0 = __expf(m - nm), s1 = __expf(om - nm);
        const float lt = l * s0 + ol * s1;
        const float inv = (lt > 0.f) ? (1.f / lt) : 0.f;
        float r0 = fmaxf((c0 * s0 + oc0 * s1) * inv, 0.f);
        float r1 = fmaxf((c1 * s0 + oc1 * s1) * inv, 0.f);
        float r2 = fmaxf((c2 * s0 + oc2 * s1) * inv, 0.f);
        float r3 = fmaxf((c3 * s0 + oc3 * s1) * inv, 0.f);

        r0 += __shfl_xor(r0, 8);  r0 += __shfl_xor(r0, 16);
        r1 += __shfl_xor(r1, 8);  r1 += __shfl_xor(r1, 16);
        r2 += __shfl_xor(r2, 8);  r2 += __shfl_xor(r2, 16);
        r3 += __shfl_xor(r3, 8);  r3 += __shfl_xor(r3, 16);
        if (lane < 8) {
            float4 o = {0.25f * r0, 0.25f * r1, 0.25f * r2, 0.25f * r3};
            *(float4*)&out[(size_t)n * NF + lane * 4] = o;
        }
    }
}

extern "C" void kernel_launch(void* const* d_in, const int* in_sizes, int n_in,
                              void* d_out, int out_size, void* d_ws, size_t ws_size,
                              hipStream_t stream)
{
    const float* nodes = (const float*)d_in[0];
    const float* W1    = (const float*)d_in[1];
    const float* b1    = (const float*)d_in[2];
    const float* g1    = (const float*)d_in[3];
    const float* be1   = (const float*)d_in[4];
    const float* W2    = (const float*)d_in[5];
    const float* b2    = (const float*)d_in[6];
    const float* g2    = (const float*)d_in[7];
    const float* be2   = (const float*)d_in[8];
    const int* senders   = (const int*)d_in[9];
    const int* receivers = (const int*)d_in[10];

    const int N = in_sizes[0] / D;
    const int E = in_sizes[9];
    float* out = (float*)d_out;

    char* ws = (char*)d_ws;
    unsigned short* qb  = (unsigned short*)ws; ws += (size_t)N * D * 2;
    int* cnt      = (int*)ws;    ws += (size_t)N * 4;
    int* rowptr   = (int*)ws;    ws += (size_t)(N + 2) * 4;
    int* cursor   = (int*)ws;    ws += (size_t)N * 4;
    int* bsum     = (int*)ws;    ws += 256 * 4;
    int* ssend    = (int*)ws;    ws += (size_t)E * 4;

    zero_cnt_kernel<<<(N / 4 + 255) / 256, 256, 0, stream>>>(cnt, N);

    // fused 2-layer MLP -> bf16 q (replaces two 42us dense kernels)
    const int gblk = (N + 63) / 64;
    fused_mlp_kernel<<<gblk, 256, 0, stream>>>(nodes, W1, b1, g1, be1,
                                               W2, b2, g2, be2, qb, N);

    // CSR build (receiver-sorted sender list)
    const int nb = (N + 1023) / 1024;
    hist_kernel<<<(E + 255) / 256, 256, 0, stream>>>(receivers, cnt, E);
    scan_blocks_kernel<<<nb, 256, 0, stream>>>(cnt, rowptr, bsum, N);
    scan_top_kernel<<<1, 256, 0, stream>>>(bsum, nb);
    scan_add_kernel<<<(N + 255) / 256, 256, 0, stream>>>(rowptr, cursor, bsum, N, E);
    fill_kernel<<<(E + 255) / 256, 256, 0, stream>>>(senders, receivers, cursor, ssend, E);

    // fused attention + epilogue
    node_attn_kernel<<<(N + 3) / 4, 256, 0, stream>>>(qb, rowptr, ssend, out, N);
}

// Round 3
// 134.446 us; speedup vs baseline: 1.2380x; 1.2241x over previous
//
#include <hip/hip_runtime.h>

constexpr int D  = 128;   // feature dim (= H*F)
constexpr int NH = 4;     // heads
constexpr int NF = 32;    // features per head

typedef __attribute__((ext_vector_type(8))) short bfrag;   // 8 bf16 = 4 VGPR
typedef __attribute__((ext_vector_type(4))) float ffrag;   // 4 f32 acc

// bf16 RNE helpers
__device__ __forceinline__ unsigned short bf16h(float x) {
    unsigned u = __float_as_uint(x);
    u += 0x7fffu + ((u >> 16) & 1u);
    return (unsigned short)(u >> 16);
}
__device__ __forceinline__ float bf16tof(unsigned short h) {
    return __uint_as_float(((unsigned)h) << 16);
}

// ---- zero the histogram counters ----
__global__ __launch_bounds__(256) void zero_cnt_kernel(int* __restrict__ p, int n)
{
    const int i4 = (blockIdx.x * blockDim.x + threadIdx.x) * 4;
    if (i4 + 3 < n) {
        *(int4*)&p[i4] = {0, 0, 0, 0};
    } else if (i4 < n) {
        for (int i = i4; i < n; ++i) p[i] = 0;
    }
}

// ---- one-time: split W1,W2 into bf16 hi/lo planes, transposed to [c][k] ----
// wt layout: L1hi[128*128], L1lo, L2hi, L2lo (ushort each)
__global__ __launch_bounds__(256) void wsplit_kernel(
    const float* __restrict__ W1, const float* __restrict__ W2,
    unsigned short* __restrict__ wt)
{
    __shared__ float T[32][33];
    const int L  = blockIdx.x >> 4;
    const int t  = blockIdx.x & 15;
    const int tr = t >> 2, tc = t & 3;
    const float* W = L ? W2 : W1;
    unsigned short* Hp = wt + (size_t)L * 32768;
    unsigned short* Lp = Hp + 16384;
    const int tx = threadIdx.x & 31, ty = threadIdx.x >> 5;
    #pragma unroll
    for (int i = 0; i < 4; ++i)
        T[ty + 8*i][tx] = W[(size_t)(tr*32 + ty + 8*i) * 128 + tc*32 + tx];
    __syncthreads();
    #pragma unroll
    for (int i = 0; i < 4; ++i) {
        const int c = tc*32 + ty + 8*i;
        const int k = tr*32 + tx;
        const float v = T[tx][ty + 8*i];
        const unsigned short hh = bf16h(v);
        const unsigned short ll = bf16h(v - bf16tof(hh));
        Hp[c*128 + k] = hh;
        Lp[c*128 + k] = ll;
    }
}

// ---- MFMA MLP: [Dense(128->128) + LN + ReLU] x2, split-bf16 (3-mfma ~ fp32) ----
// BM=64 rows/block, 4 waves; wave w owns rows w*16..w*16+15, all 128 cols.
// W staged per 64-col half. LDS pitch 136 bf16 (16B-aligned frags, <=2-way banks).
__global__ __launch_bounds__(256, 2) void mlp_mfma_kernel(
    const float* __restrict__ X,
    const unsigned short* __restrict__ WT,
    const float* __restrict__ b1, const float* __restrict__ g1, const float* __restrict__ be1,
    const float* __restrict__ b2, const float* __restrict__ g2, const float* __restrict__ be2,
    unsigned short* __restrict__ Q, int N)
{
    constexpr int P = 136;                       // LDS pitch (bf16 elems)
    __shared__ unsigned short Xh[64 * P];
    __shared__ unsigned short Xl[64 * P];
    __shared__ unsigned short Wh[64 * P];
    __shared__ unsigned short Wl[64 * P];

    const int tid  = threadIdx.x;
    const int lane = tid & 63;
    const int wave = tid >> 6;
    const int n0   = blockIdx.x * 64;
    const int lc   = lane & 15;                  // col-in-tile / A-row-in-tile
    const int lg   = lane >> 4;                  // k-group / D-row-group

    // ---- stage X (fp32 -> split bf16) ----
    #pragma unroll
    for (int j = 0; j < 8; ++j) {
        const int idx = tid + 256 * j;           // 2048 float4
        const int row = idx >> 5;
        const int c4  = (idx & 31) * 4;
        float4 v = {0, 0, 0, 0};
        if (n0 + row < N) v = *(const float4*)&X[(size_t)(n0 + row) * 128 + c4];
        const unsigned short h0 = bf16h(v.x), h1 = bf16h(v.y),
                             h2 = bf16h(v.z), h3 = bf16h(v.w);
        const unsigned short q0 = bf16h(v.x - bf16tof(h0)),
                             q1 = bf16h(v.y - bf16tof(h1)),
                             q2 = bf16h(v.z - bf16tof(h2)),
                             q3 = bf16h(v.w - bf16tof(h3));
        uint2 ph, pl;
        ph.x = (unsigned)h0 | ((unsigned)h1 << 16);
        ph.y = (unsigned)h2 | ((unsigned)h3 << 16);
        pl.x = (unsigned)q0 | ((unsigned)q1 << 16);
        pl.y = (unsigned)q2 | ((unsigned)q3 << 16);
        *(uint2*)&Xh[row * P + c4] = ph;
        *(uint2*)&Xl[row * P + c4] = pl;
    }

    // ---- helpers ----
    auto stageW = [&](const unsigned short* Hg, const unsigned short* Lg, int half) {
        #pragma unroll
        for (int j = 0; j < 4; ++j) {
            const int u = tid + 256 * j;         // 1024 uint4 per plane
            const int c = u >> 4;
            const int t = (u & 15) * 8;
            *(uint4*)&Wh[c * P + t] = *(const uint4*)&Hg[(size_t)(half*64 + c) * 128 + t];
            *(uint4*)&Wl[c * P + t] = *(const uint4*)&Lg[(size_t)(half*64 + c) * 128 + t];
        }
    };

    bfrag ah[4], al[4];
    auto loadA = [&]() {
        const int arow = wave * 16 + lc;
        #pragma unroll
        for (int ks = 0; ks < 4; ++ks) {
            ah[ks] = *(const bfrag*)&Xh[arow * P + ks * 32 + lg * 8];
            al[ks] = *(const bfrag*)&Xl[arow * P + ks * 32 + lg * 8];
        }
    };

    ffrag acc[8];
    auto gemmHalf = [&](int half) {
        #pragma unroll
        for (int ct = 0; ct < 4; ++ct) {
            const int crow = ct * 16 + lc;
            bfrag bh[4], bl[4];
            #pragma unroll
            for (int ks = 0; ks < 4; ++ks) {
                bh[ks] = *(const bfrag*)&Wh[crow * P + ks * 32 + lg * 8];
                bl[ks] = *(const bfrag*)&Wl[crow * P + ks * 32 + lg * 8];
            }
            ffrag a = acc[half * 4 + ct];
            #pragma unroll
            for (int ks = 0; ks < 4; ++ks) {
                a = __builtin_amdgcn_mfma_f32_16x16x32_bf16(ah[ks], bh[ks], a, 0, 0, 0);
                a = __builtin_amdgcn_mfma_f32_16x16x32_bf16(ah[ks], bl[ks], a, 0, 0, 0);
                a = __builtin_amdgcn_mfma_f32_16x16x32_bf16(al[ks], bh[ks], a, 0, 0, 0);
            }
            acc[half * 4 + ct] = a;
        }
    };

    const unsigned short* W1h = WT;
    const unsigned short* W1l = WT + 16384;
    const unsigned short* W2h = WT + 32768;
    const unsigned short* W2l = WT + 49152;

    // ================= layer 1 =================
    #pragma unroll
    for (int i = 0; i < 8; ++i) acc[i] = (ffrag){0.f, 0.f, 0.f, 0.f};

    stageW(W1h, W1l, 0);
    __syncthreads();                 // X + W half0 ready
    loadA();
    gemmHalf(0);
    __syncthreads();                 // half0 reads done
    stageW(W1h, W1l, 1);
    __syncthreads();                 // half1 ready
    gemmHalf(1);

    // LN1 + ReLU -> split bf16 back into Xh/Xl (own rows only; no barrier needed)
    {
        float bb[8], gg[8], tt[8];
        #pragma unroll
        for (int ct = 0; ct < 8; ++ct) {
            const int col = ct * 16 + lc;
            bb[ct] = b1[col]; gg[ct] = g1[col]; tt[ct] = be1[col];
        }
        #pragma unroll
        for (int j = 0; j < 4; ++j) {
            float t[8], s = 0.f, ss = 0.f;
            #pragma unroll
            for (int ct = 0; ct < 8; ++ct) {
                t[ct] = acc[ct][j] + bb[ct];
                s += t[ct]; ss += t[ct] * t[ct];
            }
            #pragma unroll
            for (int off = 1; off <= 8; off <<= 1) {
                s  += __shfl_xor(s,  off, 16);
                ss += __shfl_xor(ss, off, 16);
            }
            const float mu   = s * (1.f / 128.f);
            const float var  = fmaxf(ss * (1.f / 128.f) - mu * mu, 0.f);
            const float rstd = rsqrtf(var + 1e-6f);
            const int rl = wave * 16 + lg * 4 + j;
            #pragma unroll
            for (int ct = 0; ct < 8; ++ct) {
                const float o = fmaxf((t[ct] - mu) * rstd * gg[ct] + tt[ct], 0.f);
                const unsigned short hh = bf16h(o);
                const unsigned short ll = bf16h(o - bf16tof(hh));
                Xh[rl * P + ct * 16 + lc] = hh;
                Xl[rl * P + ct * 16 + lc] = ll;
            }
        }
    }

    // ================= layer 2 =================
    #pragma unroll
    for (int i = 0; i < 8; ++i) acc[i] = (ffrag){0.f, 0.f, 0.f, 0.f};

    __syncthreads();                 // layer1 W reads done (before overwrite)
    stageW(W2h, W2l, 0);
    __syncthreads();                 // half0 ready
    loadA();                         // re-read A frags (h1)
    gemmHalf(0);
    __syncthreads();                 // half0 reads done
    stageW(W2h, W2l, 1);
    __syncthreads();                 // half1 ready
    gemmHalf(1);

    // LN2 + ReLU -> bf16 q (global)
    {
        float bb[8], gg[8], tt[8];
        #pragma unroll
        for (int ct = 0; ct < 8; ++ct) {
            const int col = ct * 16 + lc;
            bb[ct] = b2[col]; gg[ct] = g2[col]; tt[ct] = be2[col];
        }
        #pragma unroll
        for (int j = 0; j < 4; ++j) {
            float t[8], s = 0.f, ss = 0.f;
            #pragma unroll
            for (int ct = 0; ct < 8; ++ct) {
                t[ct] = acc[ct][j] + bb[ct];
                s += t[ct]; ss += t[ct] * t[ct];
            }
            #pragma unroll
            for (int off = 1; off <= 8; off <<= 1) {
                s  += __shfl_xor(s,  off, 16);
                ss += __shfl_xor(ss, off, 16);
            }
            const float mu   = s * (1.f / 128.f);
            const float var  = fmaxf(ss * (1.f / 128.f) - mu * mu, 0.f);
            const float rstd = rsqrtf(var + 1e-6f);
            const int grow = n0 + wave * 16 + lg * 4 + j;
            if (grow < N) {
                #pragma unroll
                for (int ct = 0; ct < 8; ++ct) {
                    const float o = fmaxf((t[ct] - mu) * rstd * gg[ct] + tt[ct], 0.f);
                    Q[(size_t)grow * 128 + ct * 16 + lc] = bf16h(o);
                }
            }
        }
    }
}

// ---- CSR build: histogram ----
__global__ __launch_bounds__(256) void hist_kernel(
    const int* __restrict__ recv, int* __restrict__ cnt, int E)
{
    int i = blockIdx.x * blockDim.x + threadIdx.x;
    if (i < E) atomicAdd(&cnt[recv[i]], 1);
}

// ---- CSR build: per-1024-chunk exclusive scan ----
__global__ __launch_bounds__(256) void scan_blocks_kernel(
    const int* __restrict__ cnt, int* __restrict__ rowptr,
    int* __restrict__ bsum, int N)
{
    __shared__ int lds[256];
    const int tid = threadIdx.x;
    const int base = blockIdx.x * 1024 + tid * 4;
    int v0 = (base + 0 < N) ? cnt[base + 0] : 0;
    int v1 = (base + 1 < N) ? cnt[base + 1] : 0;
    int v2 = (base + 2 < N) ? cnt[base + 2] : 0;
    int v3 = (base + 3 < N) ? cnt[base + 3] : 0;
    const int tsum = v0 + v1 + v2 + v3;
    lds[tid] = tsum;
    __syncthreads();
    for (int off = 1; off < 256; off <<= 1) {
        int t = (tid >= off) ? lds[tid - off] : 0;
        __syncthreads();
        lds[tid] += t;
        __syncthreads();
    }
    int run = lds[tid] - tsum;
    if (base + 0 < N) rowptr[base + 0] = run;
    run += v0;
    if (base + 1 < N) rowptr[base + 1] = run;
    run += v1;
    if (base + 2 < N) rowptr[base + 2] = run;
    run += v2;
    if (base + 3 < N) rowptr[base + 3] = run;
    if (tid == 255) bsum[blockIdx.x] = lds[255];
}

// ---- CSR build: scan block sums ----
__global__ __launch_bounds__(256) void scan_top_kernel(int* bsum, int nb)
{
    __shared__ int lds[256];
    const int tid = threadIdx.x;
    int v = (tid < nb) ? bsum[tid] : 0;
    lds[tid] = v;
    __syncthreads();
    for (int off = 1; off < 256; off <<= 1) {
        int t = (tid >= off) ? lds[tid - off] : 0;
        __syncthreads();
        lds[tid] += t;
        __syncthreads();
    }
    if (tid < nb) bsum[tid] = lds[tid] - v;
}

// ---- CSR build: add chunk offsets ----
__global__ __launch_bounds__(256) void scan_add_kernel(
    int* __restrict__ rowptr, int* __restrict__ cursor,
    const int* __restrict__ bsum, int N, int E)
{
    int i = blockIdx.x * blockDim.x + threadIdx.x;
    if (i < N) {
        int v = rowptr[i] + bsum[i >> 10];
        rowptr[i] = v;
        cursor[i] = v;
    }
    if (i == 0) rowptr[N] = E;
}

// ---- CSR build: bucket-fill sorted sender ids ----
__global__ __launch_bounds__(256) void fill_kernel(
    const int* __restrict__ senders, const int* __restrict__ receivers,
    int* __restrict__ cursor, int* __restrict__ ssend, int E)
{
    int e = blockIdx.x * blockDim.x + threadIdx.x;
    if (e < E) {
        int r = receivers[e];
        int pos = atomicAdd(&cursor[r], 1);
        ssend[pos] = senders[e];
    }
}

// ---- fused per-node attention (bf16 q) ----
__global__ __launch_bounds__(256) void node_attn_kernel(
    const unsigned short* __restrict__ q, const int* __restrict__ rowptr,
    const int* __restrict__ ssend, float* __restrict__ out, int N)
{
    const int lane = threadIdx.x & 63;
    const int hl   = lane & 31;
    const int half = lane >> 5;
    const int wid  = (blockIdx.x * blockDim.x + threadIdx.x) >> 6;
    const int nw   = (gridDim.x * blockDim.x) >> 6;

    for (int n = wid; n < N; n += nw) {
        const uint2 braw = *(const uint2*)&q[(size_t)n * D + hl * 4];
        const float b0 = __uint_as_float(braw.x << 16);
        const float b1 = __uint_as_float(braw.x & 0xffff0000u);
        const float b2 = __uint_as_float(braw.y << 16);
        const float b3 = __uint_as_float(braw.y & 0xffff0000u);

        const int beg = rowptr[n], end = rowptr[n + 1];
        float m = -1e30f, l = 0.f;
        float c0 = 0.f, c1 = 0.f, c2 = 0.f, c3 = 0.f;

        int j = beg + half;
        uint2 raw = {0u, 0u};
        if (j < end)
            raw = *(const uint2*)&q[(size_t)ssend[j] * D + hl * 4];
        for (; j < end; j += 2) {
            const uint2 cur = raw;
            if (j + 2 < end)
                raw = *(const uint2*)&q[(size_t)ssend[j + 2] * D + hl * 4];
            const float a0 = __uint_as_float(cur.x << 16);
            const float a1 = __uint_as_float(cur.x & 0xffff0000u);
            const float a2 = __uint_as_float(cur.y << 16);
            const float a3 = __uint_as_float(cur.y & 0xffff0000u);
            float p = a0 * b0 + a1 * b1 + a2 * b2 + a3 * b3;
            p += __shfl_xor(p, 1);
            p += __shfl_xor(p, 2);
            p += __shfl_xor(p, 4);
            const float logit = p * 0.17677669529663687f;   // 1/sqrt(32)
            const float nm = fmaxf(m, logit);
            const float sc = __expf(m - nm);
            const float u  = __expf(logit - nm);
            l  = l * sc + u;
            c0 = c0 * sc + u * a0;
            c1 = c1 * sc + u * a1;
            c2 = c2 * sc + u * a2;
            c3 = c3 * sc + u * a3;
            m = nm;
        }

        const float om  = __shfl_xor(m, 32);
        const float ol  = __shfl_xor(l, 32);
        const float oc0 = __shfl_xor(c0, 32);
        const float oc1 = __shfl_xor(c1, 32);
        const float oc2 = __shfl_xor(c2, 32);
        const float oc3 = __shfl_xor(c3, 32);
        const float nm = fmaxf(m, om);
        const float s0 = __expf(m - nm), s1 = __expf(om - nm);
        const float lt = l * s0 + ol * s1;
        const float inv = (lt > 0.f) ? (1.f / lt) : 0.f;
        float r0 = fmaxf((c0 * s0 + oc0 * s1) * inv, 0.f);
        float r1 = fmaxf((c1 * s0 + oc1 * s1) * inv, 0.f);
        float r2 = fmaxf((c2 * s0 + oc2 * s1) * inv, 0.f);
        float r3 = fmaxf((c3 * s0 + oc3 * s1) * inv, 0.f);

        r0 += __shfl_xor(r0, 8);  r0 += __shfl_xor(r0, 16);
        r1 += __shfl_xor(r1, 8);  r1 += __shfl_xor(r1, 16);
        r2 += __shfl_xor(r2, 8);  r2 += __shfl_xor(r2, 16);
        r3 += __shfl_xor(r3, 8);  r3 += __shfl_xor(r3, 16);
        if (lane < 8) {
            float4 o = {0.25f * r0, 0.25f * r1, 0.25f * r2, 0.25f * r3};
            *(float4*)&out[(size_t)n * NF + lane * 4] = o;
        }
    }
}

extern "C" void kernel_launch(void* const* d_in, const int* in_sizes, int n_in,
                              void* d_out, int out_size, void* d_ws, size_t ws_size,
                              hipStream_t stream)
{
    const float* nodes = (const float*)d_in[0];
    const float* W1    = (const float*)d_in[1];
    const float* b1    = (const float*)d_in[2];
    const float* g1    = (const float*)d_in[3];
    const float* be1   = (const float*)d_in[4];
    const float* W2    = (const float*)d_in[5];
    const float* b2    = (const float*)d_in[6];
    const float* g2    = (const float*)d_in[7];
    const float* be2   = (const float*)d_in[8];
    const int* senders   = (const int*)d_in[9];
    const int* receivers = (const int*)d_in[10];

    const int N = in_sizes[0] / D;
    const int E = in_sizes[9];
    float* out = (float*)d_out;

    char* ws = (char*)d_ws;
    unsigned short* qb = (unsigned short*)ws; ws += (size_t)N * D * 2;
    unsigned short* wt = (unsigned short*)ws; ws += 4 * 128 * 128 * 2;
    int* cnt      = (int*)ws;    ws += (size_t)N * 4;
    int* rowptr   = (int*)ws;    ws += (size_t)(N + 2) * 4;
    int* cursor   = (int*)ws;    ws += (size_t)N * 4;
    int* bsum     = (int*)ws;    ws += 256 * 4;
    int* ssend    = (int*)ws;    ws += (size_t)E * 4;

    zero_cnt_kernel<<<(N / 4 + 255) / 256, 256, 0, stream>>>(cnt, N);

    // one-time weight split/transpose, then MFMA MLP -> bf16 q
    wsplit_kernel<<<32, 256, 0, stream>>>(W1, W2, wt);
    const int gblk = (N + 63) / 64;
    mlp_mfma_kernel<<<gblk, 256, 0, stream>>>(nodes, wt, b1, g1, be1,
                                              b2, g2, be2, qb, N);

    // CSR build (receiver-sorted sender list)
    const int nb = (N + 1023) / 1024;
    hist_kernel<<<(E + 255) / 256, 256, 0, stream>>>(receivers, cnt, E);
    scan_blocks_kernel<<<nb, 256, 0, stream>>>(cnt, rowptr, bsum, N);
    scan_top_kernel<<<1, 256, 0, stream>>>(bsum, nb);
    scan_add_kernel<<<(N + 255) / 256, 256, 0, stream>>>(rowptr, cursor, bsum, N, E);
    fill_kernel<<<(E + 255) / 256, 256, 0, stream>>>(senders, receivers, cursor, ssend, E);

    // fused attention + epilogue
    node_attn_kernel<<<(N + 3) / 4, 256, 0, stream>>>(qb, rowptr, ssend, out, N);
}

// Round 4
// 132.873 us; speedup vs baseline: 1.2527x; 1.0118x over previous
//
#include <hip/hip_runtime.h>

constexpr int D  = 128;   // feature dim (= H*F)
constexpr int NH = 4;     // heads
constexpr int NF = 32;    // features per head

typedef __attribute__((ext_vector_type(8))) short bfrag;   // 8 bf16 = 4 VGPR
typedef __attribute__((ext_vector_type(4))) float ffrag;   // 4 f32 acc

// bf16 RNE helpers
__device__ __forceinline__ unsigned short bf16h(float x) {
    unsigned u = __float_as_uint(x);
    u += 0x7fffu + ((u >> 16) & 1u);
    return (unsigned short)(u >> 16);
}
__device__ __forceinline__ float bf16tof(unsigned short h) {
    return __uint_as_float(((unsigned)h) << 16);
}

// ---- zero the histogram counters ----
__global__ __launch_bounds__(256) void zero_cnt_kernel(int* __restrict__ p, int n)
{
    const int i4 = (blockIdx.x * blockDim.x + threadIdx.x) * 4;
    if (i4 + 3 < n) {
        *(int4*)&p[i4] = {0, 0, 0, 0};
    } else if (i4 < n) {
        for (int i = i4; i < n; ++i) p[i] = 0;
    }
}

// ---- one-time: split W1,W2 into bf16 hi/lo planes, FRAGMENT-ORDERED ----
// Output: 1KB chunks indexed ((L*2+plane)*32 + ct*4 + ks); chunk[lane][i] =
// plane(W[ks*32 + (lane>>4)*8 + i][ct*16 + (lane&15)]).  A B-frag load is then
// one coalesced global_load_dwordx4 at chunkbase + lane*16B.
__global__ __launch_bounds__(256) void wsplit_kernel(
    const float* __restrict__ W1, const float* __restrict__ W2,
    unsigned short* __restrict__ wt)
{
    const int L  = blockIdx.x >> 3;          // 16 blocks: L in {0,1}, ct in 0..7
    const int ct = blockIdx.x & 7;
    const float* W = L ? W2 : W1;
    const int ks   = threadIdx.x >> 6;
    const int lane = threadIdx.x & 63;
    const int lg = lane >> 4, lc = lane & 15;
    unsigned short* Hp = wt + ((size_t)(L * 2 + 0) * 32 + ct * 4 + ks) * 512 + lane * 8;
    unsigned short* Lp = wt + ((size_t)(L * 2 + 1) * 32 + ct * 4 + ks) * 512 + lane * 8;
    #pragma unroll
    for (int i = 0; i < 8; ++i) {
        const int k = ks * 32 + lg * 8 + i;
        const int c = ct * 16 + lc;
        const float v = W[(size_t)k * 128 + c];
        const unsigned short hh = bf16h(v);
        Hp[i] = hh;
        Lp[i] = bf16h(v - bf16tof(hh));
    }
}

// ---- MFMA MLP, zero-barrier: each wave owns 16 rows end-to-end ----
// A-frags from global X (in-reg hi/lo split). B-frags from fragment-ordered
// global W (L1/L2-resident). h1 transposed through an 8.4KB per-wave LDS
// scratch (u32 = hi|lo<<16), wave-local s_waitcnt only — no __syncthreads.
__global__ __launch_bounds__(256, 4) void mlp_mfma_kernel(
    const float* __restrict__ X,
    const unsigned short* __restrict__ WF,
    const float* __restrict__ b1, const float* __restrict__ g1, const float* __restrict__ be1,
    const float* __restrict__ b2, const float* __restrict__ g2, const float* __restrict__ be2,
    unsigned short* __restrict__ Q, int N)
{
    constexpr int PW = 132;                    // u32 pitch (528B = 33*16, b128-aligned)
    __shared__ unsigned HL[4 * 16 * PW];       // 33792 B

    const int tid  = threadIdx.x;
    const int lane = tid & 63;
    const int wave = tid >> 6;
    const int lc   = lane & 15;
    const int lg   = lane >> 4;
    const int n0w  = (blockIdx.x * 4 + wave) * 16;
    if (n0w >= N) return;
    unsigned* hl = &HL[wave * 16 * PW];

    bfrag ah[4], al[4];
    ffrag acc[8];

    // ---- A-frags for layer 1: direct from global X, split in-reg ----
    {
        const int rowx = (n0w + lc < N) ? (n0w + lc) : (N - 1);
        const float* xr = X + (size_t)rowx * 128 + lg * 8;
        #pragma unroll
        for (int ks = 0; ks < 4; ++ks) {
            const float4 a = *(const float4*)&xr[ks * 32];
            const float4 b = *(const float4*)&xr[ks * 32 + 4];
            const float f[8] = {a.x, a.y, a.z, a.w, b.x, b.y, b.z, b.w};
            #pragma unroll
            for (int i = 0; i < 8; ++i) {
                const unsigned short hh = bf16h(f[i]);
                ah[ks][i] = (short)hh;
                al[ks][i] = (short)bf16h(f[i] - bf16tof(hh));
            }
        }
    }

    // ---- gemm: 8 col-tiles x 4 k-steps x 3 mfma (split-bf16 ~ fp32) ----
    auto gemm = [&](int hiBase, int loBase) {
        #pragma unroll
        for (int ct = 0; ct < 8; ++ct) {
            const unsigned short* bhp = WF + (size_t)(hiBase + ct * 4) * 512 + lane * 8;
            const unsigned short* blp = WF + (size_t)(loBase + ct * 4) * 512 + lane * 8;
            bfrag bh[4], bl[4];
            #pragma unroll
            for (int ks = 0; ks < 4; ++ks) {
                bh[ks] = *(const bfrag*)(bhp + ks * 512);
                bl[ks] = *(const bfrag*)(blp + ks * 512);
            }
            ffrag a = acc[ct];
            #pragma unroll
            for (int ks = 0; ks < 4; ++ks) {
                a = __builtin_amdgcn_mfma_f32_16x16x32_bf16(ah[ks], bh[ks], a, 0, 0, 0);
                a = __builtin_amdgcn_mfma_f32_16x16x32_bf16(ah[ks], bl[ks], a, 0, 0, 0);
                a = __builtin_amdgcn_mfma_f32_16x16x32_bf16(al[ks], bh[ks], a, 0, 0, 0);
            }
            acc[ct] = a;
        }
    };

    // ================= layer 1 =================
    #pragma unroll
    for (int i = 0; i < 8; ++i) acc[i] = (ffrag){0.f, 0.f, 0.f, 0.f};
    gemm(0, 32);

    // LN1 + ReLU -> packed hi|lo u32 into per-wave LDS ([row][col=k])
    {
        float bb[8], gg[8], tt[8];
        #pragma unroll
        for (int ct = 0; ct < 8; ++ct) {
            const int col = ct * 16 + lc;
            bb[ct] = b1[col]; gg[ct] = g1[col]; tt[ct] = be1[col];
        }
        #pragma unroll
        for (int j = 0; j < 4; ++j) {
            float t[8], s = 0.f, ss = 0.f;
            #pragma unroll
            for (int ct = 0; ct < 8; ++ct) {
                t[ct] = acc[ct][j] + bb[ct];
                s += t[ct]; ss += t[ct] * t[ct];
            }
            #pragma unroll
            for (int off = 1; off <= 8; off <<= 1) {
                s  += __shfl_xor(s,  off, 16);
                ss += __shfl_xor(ss, off, 16);
            }
            const float mu   = s * (1.f / 128.f);
            const float var  = fmaxf(ss * (1.f / 128.f) - mu * mu, 0.f);
            const float rstd = rsqrtf(var + 1e-6f);
            const int row = lg * 4 + j;
            #pragma unroll
            for (int ct = 0; ct < 8; ++ct) {
                const float o = fmaxf((t[ct] - mu) * rstd * gg[ct] + tt[ct], 0.f);
                const unsigned short hh = bf16h(o);
                const unsigned short ll = bf16h(o - bf16tof(hh));
                hl[row * PW + ct * 16 + lc] = (unsigned)hh | ((unsigned)ll << 16);
            }
        }
    }

    // wave-local fence: all 64 lanes' LDS writes complete before cross-lane reads
    asm volatile("s_waitcnt lgkmcnt(0)" ::: "memory");

    // ---- A-frags for layer 2: from packed LDS (row = lc, k = ks*32+lg*8+i) ----
    #pragma unroll
    for (int ks = 0; ks < 4; ++ks) {
        const uint4 r0 = *(const uint4*)&hl[lc * PW + ks * 32 + lg * 8];
        const uint4 r1 = *(const uint4*)&hl[lc * PW + ks * 32 + lg * 8 + 4];
        const unsigned rr[8] = {r0.x, r0.y, r0.z, r0.w, r1.x, r1.y, r1.z, r1.w};
        #pragma unroll
        for (int i = 0; i < 8; ++i) {
            ah[ks][i] = (short)(rr[i] & 0xffffu);
            al[ks][i] = (short)(rr[i] >> 16);
        }
    }

    // ================= layer 2 =================
    #pragma unroll
    for (int i = 0; i < 8; ++i) acc[i] = (ffrag){0.f, 0.f, 0.f, 0.f};
    gemm(64, 96);

    // LN2 + ReLU -> bf16 q (global)
    {
        float bb[8], gg[8], tt[8];
        #pragma unroll
        for (int ct = 0; ct < 8; ++ct) {
            const int col = ct * 16 + lc;
            bb[ct] = b2[col]; gg[ct] = g2[col]; tt[ct] = be2[col];
        }
        #pragma unroll
        for (int j = 0; j < 4; ++j) {
            float t[8], s = 0.f, ss = 0.f;
            #pragma unroll
            for (int ct = 0; ct < 8; ++ct) {
                t[ct] = acc[ct][j] + bb[ct];
                s += t[ct]; ss += t[ct] * t[ct];
            }
            #pragma unroll
            for (int off = 1; off <= 8; off <<= 1) {
                s  += __shfl_xor(s,  off, 16);
                ss += __shfl_xor(ss, off, 16);
            }
            const float mu   = s * (1.f / 128.f);
            const float var  = fmaxf(ss * (1.f / 128.f) - mu * mu, 0.f);
            const float rstd = rsqrtf(var + 1e-6f);
            const int grow = n0w + lg * 4 + j;
            if (grow < N) {
                #pragma unroll
                for (int ct = 0; ct < 8; ++ct) {
                    const float o = fmaxf((t[ct] - mu) * rstd * gg[ct] + tt[ct], 0.f);
                    Q[(size_t)grow * 128 + ct * 16 + lc] = bf16h(o);
                }
            }
        }
    }
}

// ---- CSR build: histogram ----
__global__ __launch_bounds__(256) void hist_kernel(
    const int* __restrict__ recv, int* __restrict__ cnt, int E)
{
    int i = blockIdx.x * blockDim.x + threadIdx.x;
    if (i < E) atomicAdd(&cnt[recv[i]], 1);
}

// ---- CSR build: per-1024-chunk exclusive scan ----
__global__ __launch_bounds__(256) void scan_blocks_kernel(
    const int* __restrict__ cnt, int* __restrict__ rowptr,
    int* __restrict__ bsum, int N)
{
    __shared__ int lds[256];
    const int tid = threadIdx.x;
    const int base = blockIdx.x * 1024 + tid * 4;
    int v0 = (base + 0 < N) ? cnt[base + 0] : 0;
    int v1 = (base + 1 < N) ? cnt[base + 1] : 0;
    int v2 = (base + 2 < N) ? cnt[base + 2] : 0;
    int v3 = (base + 3 < N) ? cnt[base + 3] : 0;
    const int tsum = v0 + v1 + v2 + v3;
    lds[tid] = tsum;
    __syncthreads();
    for (int off = 1; off < 256; off <<= 1) {
        int t = (tid >= off) ? lds[tid - off] : 0;
        __syncthreads();
        lds[tid] += t;
        __syncthreads();
    }
    int run = lds[tid] - tsum;
    if (base + 0 < N) rowptr[base + 0] = run;
    run += v0;
    if (base + 1 < N) rowptr[base + 1] = run;
    run += v1;
    if (base + 2 < N) rowptr[base + 2] = run;
    run += v2;
    if (base + 3 < N) rowptr[base + 3] = run;
    if (tid == 255) bsum[blockIdx.x] = lds[255];
}

// ---- CSR build: scan block sums ----
__global__ __launch_bounds__(256) void scan_top_kernel(int* bsum, int nb)
{
    __shared__ int lds[256];
    const int tid = threadIdx.x;
    int v = (tid < nb) ? bsum[tid] : 0;
    lds[tid] = v;
    __syncthreads();
    for (int off = 1; off < 256; off <<= 1) {
        int t = (tid >= off) ? lds[tid - off] : 0;
        __syncthreads();
        lds[tid] += t;
        __syncthreads();
    }
    if (tid < nb) bsum[tid] = lds[tid] - v;
}

// ---- CSR build: add chunk offsets ----
__global__ __launch_bounds__(256) void scan_add_kernel(
    int* __restrict__ rowptr, int* __restrict__ cursor,
    const int* __restrict__ bsum, int N, int E)
{
    int i = blockIdx.x * blockDim.x + threadIdx.x;
    if (i < N) {
        int v = rowptr[i] + bsum[i >> 10];
        rowptr[i] = v;
        cursor[i] = v;
    }
    if (i == 0) rowptr[N] = E;
}

// ---- CSR build: bucket-fill sorted sender ids ----
__global__ __launch_bounds__(256) void fill_kernel(
    const int* __restrict__ senders, const int* __restrict__ receivers,
    int* __restrict__ cursor, int* __restrict__ ssend, int E)
{
    int e = blockIdx.x * blockDim.x + threadIdx.x;
    if (e < E) {
        int r = receivers[e];
        int pos = atomicAdd(&cursor[r], 1);
        ssend[pos] = senders[e];
    }
}

// ---- fused per-node attention (bf16 q) ----
__global__ __launch_bounds__(256) void node_attn_kernel(
    const unsigned short* __restrict__ q, const int* __restrict__ rowptr,
    const int* __restrict__ ssend, float* __restrict__ out, int N)
{
    const int lane = threadIdx.x & 63;
    const int hl   = lane & 31;
    const int half = lane >> 5;
    const int wid  = (blockIdx.x * blockDim.x + threadIdx.x) >> 6;
    const int nw   = (gridDim.x * blockDim.x) >> 6;

    for (int n = wid; n < N; n += nw) {
        const uint2 braw = *(const uint2*)&q[(size_t)n * D + hl * 4];
        const float b0 = __uint_as_float(braw.x << 16);
        const float b1 = __uint_as_float(braw.x & 0xffff0000u);
        const float b2 = __uint_as_float(braw.y << 16);
        const float b3 = __uint_as_float(braw.y & 0xffff0000u);

        const int beg = rowptr[n], end = rowptr[n + 1];
        float m = -1e30f, l = 0.f;
        float c0 = 0.f, c1 = 0.f, c2 = 0.f, c3 = 0.f;

        int j = beg + half;
        uint2 raw = {0u, 0u};
        if (j < end)
            raw = *(const uint2*)&q[(size_t)ssend[j] * D + hl * 4];
        for (; j < end; j += 2) {
            const uint2 cur = raw;
            if (j + 2 < end)
                raw = *(const uint2*)&q[(size_t)ssend[j + 2] * D + hl * 4];
            const float a0 = __uint_as_float(cur.x << 16);
            const float a1 = __uint_as_float(cur.x & 0xffff0000u);
            const float a2 = __uint_as_float(cur.y << 16);
            const float a3 = __uint_as_float(cur.y & 0xffff0000u);
            float p = a0 * b0 + a1 * b1 + a2 * b2 + a3 * b3;
            p += __shfl_xor(p, 1);
            p += __shfl_xor(p, 2);
            p += __shfl_xor(p, 4);
            const float logit = p * 0.17677669529663687f;   // 1/sqrt(32)
            const float nm = fmaxf(m, logit);
            const float sc = __expf(m - nm);
            const float u  = __expf(logit - nm);
            l  = l * sc + u;
            c0 = c0 * sc + u * a0;
            c1 = c1 * sc + u * a1;
            c2 = c2 * sc + u * a2;
            c3 = c3 * sc + u * a3;
            m = nm;
        }

        const float om  = __shfl_xor(m, 32);
        const float ol  = __shfl_xor(l, 32);
        const float oc0 = __shfl_xor(c0, 32);
        const float oc1 = __shfl_xor(c1, 32);
        const float oc2 = __shfl_xor(c2, 32);
        const float oc3 = __shfl_xor(c3, 32);
        const float nm = fmaxf(m, om);
        const float s0 = __expf(m - nm), s1 = __expf(om - nm);
        const float lt = l * s0 + ol * s1;
        const float inv = (lt > 0.f) ? (1.f / lt) : 0.f;
        float r0 = fmaxf((c0 * s0 + oc0 * s1) * inv, 0.f);
        float r1 = fmaxf((c1 * s0 + oc1 * s1) * inv, 0.f);
        float r2 = fmaxf((c2 * s0 + oc2 * s1) * inv, 0.f);
        float r3 = fmaxf((c3 * s0 + oc3 * s1) * inv, 0.f);

        r0 += __shfl_xor(r0, 8);  r0 += __shfl_xor(r0, 16);
        r1 += __shfl_xor(r1, 8);  r1 += __shfl_xor(r1, 16);
        r2 += __shfl_xor(r2, 8);  r2 += __shfl_xor(r2, 16);
        r3 += __shfl_xor(r3, 8);  r3 += __shfl_xor(r3, 16);
        if (lane < 8) {
            float4 o = {0.25f * r0, 0.25f * r1, 0.25f * r2, 0.25f * r3};
            *(float4*)&out[(size_t)n * NF + lane * 4] = o;
        }
    }
}

extern "C" void kernel_launch(void* const* d_in, const int* in_sizes, int n_in,
                              void* d_out, int out_size, void* d_ws, size_t ws_size,
                              hipStream_t stream)
{
    const float* nodes = (const float*)d_in[0];
    const float* W1    = (const float*)d_in[1];
    const float* b1    = (const float*)d_in[2];
    const float* g1    = (const float*)d_in[3];
    const float* be1   = (const float*)d_in[4];
    const float* W2    = (const float*)d_in[5];
    const float* b2    = (const float*)d_in[6];
    const float* g2    = (const float*)d_in[7];
    const float* be2   = (const float*)d_in[8];
    const int* senders   = (const int*)d_in[9];
    const int* receivers = (const int*)d_in[10];

    const int N = in_sizes[0] / D;
    const int E = in_sizes[9];
    float* out = (float*)d_out;

    char* ws = (char*)d_ws;
    unsigned short* qb = (unsigned short*)ws; ws += (size_t)N * D * 2;
    unsigned short* wt = (unsigned short*)ws; ws += 4 * 128 * 128 * 2;
    int* cnt      = (int*)ws;    ws += (size_t)N * 4;
    int* rowptr   = (int*)ws;    ws += (size_t)(N + 2) * 4;
    int* cursor   = (int*)ws;    ws += (size_t)N * 4;
    int* bsum     = (int*)ws;    ws += 256 * 4;
    int* ssend    = (int*)ws;    ws += (size_t)E * 4;

    zero_cnt_kernel<<<(N / 4 + 255) / 256, 256, 0, stream>>>(cnt, N);

    // one-time weight split to fragment-ordered layout, then zero-barrier MFMA MLP
    wsplit_kernel<<<16, 256, 0, stream>>>(W1, W2, wt);
    const int nwaves = (N + 15) / 16;
    const int gblk = (nwaves + 3) / 4;
    mlp_mfma_kernel<<<gblk, 256, 0, stream>>>(nodes, wt, b1, g1, be1,
                                              b2, g2, be2, qb, N);

    // CSR build (receiver-sorted sender list)
    const int nb = (N + 1023) / 1024;
    hist_kernel<<<(E + 255) / 256, 256, 0, stream>>>(receivers, cnt, E);
    scan_blocks_kernel<<<nb, 256, 0, stream>>>(cnt, rowptr, bsum, N);
    scan_top_kernel<<<1, 256, 0, stream>>>(bsum, nb);
    scan_add_kernel<<<(N + 255) / 256, 256, 0, stream>>>(rowptr, cursor, bsum, N, E);
    fill_kernel<<<(E + 255) / 256, 256, 0, stream>>>(senders, receivers, cursor, ssend, E);

    // fused attention + epilogue
    node_attn_kernel<<<(N + 3) / 4, 256, 0, stream>>>(qb, rowptr, ssend, out, N);
}